// Round 9
// baseline (204.111 us; speedup 1.0000x reference)
//
#include <hip/hip_runtime.h>

// Problem constants
#define NBATCH  4
#define TSEQ    2048
#define MROWS   8192
#define NCAT    1280              // 512 (a_b|a_t) + 512 (c_b|c_t) + 256 (z_t)
#define NE      512

// ---- workspace layout (float offsets) ----
#define OFF_WQT   0u                          // Wq^T bf16 [1024][1024]
#define OFF_WKT   524288u                     // Wk^T bf16 [1024][1024]
#define OFF_WOB   1048576u                    // Wo   bf16 [1024][1024]
#define OFF_VCT   1572864u                    // Vc^T bf16 [512][1024]
#define OFF_WCT   1835008u                    // Wc^T bf16 [512][1024]
#define OFF_UCT   2097152u                    // Uc^T bf16 [512][1024]
#define OFF_B2    2359296u                    // [1024] f32
#define OFF_PB    2360320u                    // PcatT bf16 [1280][1024]
#define OFF_GB    3015680u                    // G bf16 [1024][512]
#define OFF_Y     3277824u                    // Y bf16 [8192][1280] (5.24M f)
#define OFF_SCR   13763584u                   // f32 [4][32][768]
#define OFF_XB    13861888u                   // x bf16 [8192][1024]
#define OFF_EB    OFF_XB                      // E bf16 [8192][512] (aliases xb)

typedef __attribute__((ext_vector_type(8))) short bf16x8;
typedef __attribute__((ext_vector_type(4))) float f32x4;

__device__ __forceinline__ unsigned short f2bf(float f) {
  union { float f; unsigned u; } v; v.f = f;
  return (unsigned short)((v.u + 0x7fff + ((v.u >> 16) & 1)) >> 16);  // RNE
}
__device__ __forceinline__ float bf2f(unsigned short u) {
  union { unsigned u; float f; } v; v.u = ((unsigned)u) << 16;
  return v.f;
}

__device__ __forceinline__ void gload16(const void* g, void* l) {
  __builtin_amdgcn_global_load_lds(
      (const __attribute__((address_space(1))) unsigned*)g,
      (__attribute__((address_space(3))) unsigned*)l, 16, 0, 0);
}

// ===== bf16 MFMA NT tile, BK=32, 3-buffer LDS, DEPTH-3 counted vmcnt =========
// C[m0:+128][n0:+128] = A[M][K]*B[N][K]^T. 4 waves (2x2), wave 64x64.
// Per tile each thread issues exactly 4 global_load_lds. Steady state waits
// vmcnt(8): tile-t retired, tiles t+1,t+2 (8 loads) stay IN FLIGHT across the
// barrier. Tail: vmcnt(4) then vmcnt(0). Raw s_barrier only; ds_read->MFMA
// waits stay compiler-managed. Hazards: stage(t+2) writes buf((t+2)%3), last
// read at compute(t-1), sealed by iter t-1's trailing barrier; reads of buf t
// sealed by counted vmcnt + leading barrier.  Requires nt >= 2.
// LDS chunk swizzle (rule #21): LDS[c] = global[c^(r&3)] via pre-swizzled
// SOURCE (linear gload_lds dest); ds_read XORs the same involution.
// EPI: C = acc / ((m & 2047)+1) + bias[n].  OBF: C is bf16.
// CS: for n0>=512 also write 64-row column sums to scr[b][seg][col-512].
template <int EPI, int OBF, int CS>
__device__ __forceinline__ void mfma_tile(
    const short* __restrict__ A, const short* __restrict__ B, void* __restrict__ Cv,
    int K, int ldA, int ldB, int ldC, int m0, int n0,
    const float* __restrict__ bias, float* __restrict__ scr, short* L) {
  const int tid = threadIdx.x;
  const int l = tid & 63;
  const int wv = tid >> 6;
  const int wm = (wv >> 1) * 64, wn = (wv & 1) * 64;
  const int sr = tid >> 2;              // staging row 0..63 (plus p*64)
  const int sc4 = tid & 3;              // 16B chunk 0..3 within 64B row
  const int arow = wm + (l & 15), brow = wn + (l & 15);
  const int kq = l >> 4;                // k-chunk 0..3

  f32x4 acc[4][4] = {};

#define STAGE(k0, buf) do {                                                  \
    short* As_ = L + (buf) * 8192;                                           \
    short* Bs_ = As_ + 4096;                                                 \
    _Pragma("unroll")                                                        \
    for (int p = 0; p < 2; ++p) {                                            \
      const int r = p * 64 + sr;                                             \
      const int sw = (sc4 ^ (r & 3)) * 8;                                    \
      gload16(A + (size_t)(m0 + r) * ldA + (k0) + sw, As_ + r * 32 + sc4 * 8); \
      gload16(B + (size_t)(n0 + r) * ldB + (k0) + sw, Bs_ + r * 32 + sc4 * 8); \
    }                                                                        \
  } while (0)

#define COMPUTE(buf) do {                                                    \
    short* As_ = L + (buf) * 8192;                                           \
    short* Bs_ = As_ + 4096;                                                 \
    bf16x8 af[4], bfr[4];                                                    \
    _Pragma("unroll")                                                        \
    for (int m = 0; m < 4; ++m) {                                            \
      const int r = arow + m * 16;                                           \
      af[m] = *(const bf16x8*)&As_[r * 32 + ((kq ^ (r & 3)) * 8)];           \
    }                                                                        \
    _Pragma("unroll")                                                        \
    for (int n = 0; n < 4; ++n) {                                            \
      const int r = brow + n * 16;                                           \
      bfr[n] = *(const bf16x8*)&Bs_[r * 32 + ((kq ^ (r & 3)) * 8)];          \
    }                                                                        \
    _Pragma("unroll")                                                        \
    for (int m = 0; m < 4; ++m)                                              \
      _Pragma("unroll")                                                      \
      for (int n = 0; n < 4; ++n)                                            \
        acc[m][n] = __builtin_amdgcn_mfma_f32_16x16x32_bf16(af[m], bfr[n], acc[m][n], 0, 0, 0); \
  } while (0)

  STAGE(0, 0);
  STAGE(32, 1);
  const int nt = K >> 5;
  int cur = 0, nxt = 2;
  for (int t = 0; t < nt; ++t) {
    if (t + 2 < nt) {
      STAGE((t + 2) << 5, nxt);
      asm volatile("s_waitcnt vmcnt(8)" ::: "memory");   // tile t ready; 8 in flight
    } else if (t + 1 < nt) {
      asm volatile("s_waitcnt vmcnt(4)" ::: "memory");
    } else {
      asm volatile("s_waitcnt vmcnt(0)" ::: "memory");
    }
    asm volatile("s_barrier" ::: "memory");
    COMPUTE(cur);
    asm volatile("s_barrier" ::: "memory");
    cur = (cur == 2) ? 0 : cur + 1;
    nxt = (nxt == 2) ? 0 : nxt + 1;
  }
#undef STAGE
#undef COMPUTE

  // epilogue. C/D layout: col = l&15, row = (l>>4)*4 + j
  const int cc = wn + (l & 15);
  const int crb = wm + (l >> 4) * 4;
#pragma unroll
  for (int m = 0; m < 4; ++m) {
#pragma unroll
    for (int j = 0; j < 4; ++j) {
      const int gm = m0 + crb + m * 16 + j;
      float inv = 1.0f;
      if (EPI) inv = 1.0f / (float)((gm & (TSEQ - 1)) + 1);
#pragma unroll
      for (int n = 0; n < 4; ++n) {
        const int gn = n0 + cc + n * 16;
        float v = acc[m][n][j];
        if (EPI) v = v * inv + bias[gn];
        if (OBF) ((short*)Cv)[(size_t)gm * ldC + gn] = (short)f2bf(v);
        else     ((float*)Cv)[(size_t)gm * ldC + gn] = v;
      }
    }
  }
  // fused cumsum stage-1: 64-row column sums of this wave's block (f32 acc)
  if (CS && n0 >= 512) {
    const int bb = (m0 + wm) >> 11;
    const int seg = ((m0 + wm) & (TSEQ - 1)) >> 6;
    float* sp = scr + (size_t)(bb * 32 + seg) * 768 + (n0 - 512);
#pragma unroll
    for (int n = 0; n < 4; ++n) {
      float s = 0.f;
#pragma unroll
      for (int m = 0; m < 4; ++m)
#pragma unroll
        for (int j = 0; j < 4; ++j) s += acc[m][n][j];
      s += __shfl_xor(s, 16, 64);
      s += __shfl_xor(s, 32, 64);
      if (l < 16) sp[cc + n * 16] = s;
    }
  }
}

// XCD-aware bijective swizzle of the linearized block id (nwg % 8 == 0).
__device__ __forceinline__ void xcd_swizzle(int& bx, int& by) {
  const int gx = gridDim.x;
  const int nwg = gx * gridDim.y;
  const int n = by * gx + bx;
  const int q = nwg >> 3;
  const int s = (n & 7) * q + (n >> 3);
  bx = s % gx; by = s / gx;
}

template <int EPI, int OBF, int CS>
__global__ __launch_bounds__(256) void mfma_nt(
    const short* __restrict__ A, const short* __restrict__ B,
    void* __restrict__ C, int K, int ldA, int ldB, int ldC,
    const float* __restrict__ bias, float* __restrict__ scr) {
  __shared__ short L[24576];
  int bx = blockIdx.x, by = blockIdx.y;
  xcd_swizzle(bx, by);
  mfma_tile<EPI, OBF, CS>(A, B, C, K, ldA, ldB, ldC,
                          by * 128, bx * 128, bias, scr, L);
}

// batched prep: 96 blocks = 3 GEMMs x 32 tiles (all K=1024, bf16 out)
__global__ __launch_bounds__(256) void prep_mfma(
    const short* __restrict__ VCT, const short* __restrict__ WQT,
    const short* __restrict__ WCT, const short* __restrict__ WKT,
    const short* __restrict__ WOB, const short* __restrict__ UCT,
    short* __restrict__ Pb, short* __restrict__ Gb) {
  __shared__ short L[24576];
  const int g = blockIdx.x >> 5, t = blockIdx.x & 31;
  if (g == 0)
    mfma_tile<0, 1, 0>(VCT, WQT, Pb, 1024, 1024, 1024, 1024,
                       (t >> 3) * 128, (t & 7) * 128, nullptr, nullptr, L);
  else if (g == 1)
    mfma_tile<0, 1, 0>(WCT, WKT, Pb + (size_t)512 * 1024, 1024, 1024, 1024, 1024,
                       (t >> 3) * 128, (t & 7) * 128, nullptr, nullptr, L);
  else
    mfma_tile<0, 1, 0>(WOB, UCT, Gb, 1024, 1024, 1024, 512,
                       (t >> 2) * 128, (t & 3) * 128, nullptr, nullptr, L);
}

// ===== prep_all: transposes + f2b(Wo) + f2b(x) + bias_proj, one launch ========
__global__ __launch_bounds__(256) void prep_all(
    const float* __restrict__ Vb, const float* __restrict__ Vt,
    const float* __restrict__ Wb, const float* __restrict__ Wt,
    const float* __restrict__ Ub, const float* __restrict__ Ut,
    const float* __restrict__ Xt, const float* __restrict__ Wq,
    const float* __restrict__ Wk, const float* __restrict__ Wo,
    const float* __restrict__ x,
    const float* __restrict__ bias_b, const float* __restrict__ bias_t,
    const float* __restrict__ alpha_p,
    short* __restrict__ VCT, short* __restrict__ WCT, short* __restrict__ UCT,
    short* __restrict__ PbXt, short* __restrict__ WQT, short* __restrict__ WKT,
    short* __restrict__ WOB, short* __restrict__ xb, float* __restrict__ b2) {
  const int bid = blockIdx.x;
  const int tid = threadIdx.x;
  if (bid >= 10176) {                       // bias_proj: d = bid - 10176
    const float al = *alpha_p;
    const int d = bid - 10176;
    float s = 0.f;
    for (int e = tid; e < 1024; e += 256)
      s += Wo[(size_t)d * 1024 + e] * (bias_b[e] + al * bias_t[e]);
    __shared__ float red[256];
    red[tid] = s; __syncthreads();
    for (int off = 128; off > 0; off >>= 1) {
      if (tid < off) red[tid] += red[tid + off];
      __syncthreads();
    }
    if (tid == 0) b2[d] = red[0];
    return;
  }
  if (bid >= 960) {                         // f2b: Wo (1M floats) then x (8M)
    const size_t j = ((size_t)(bid - 960) * 256 + tid) * 4;
    const int isWo = j < 1048576u;
    const float* s = isWo ? &Wo[j] : &x[j - 1048576u];
    const float4 v = *(const float4*)s;
    ushort4 o;
    o.x = f2bf(v.x); o.y = f2bf(v.y); o.z = f2bf(v.z); o.w = f2bf(v.w);
    unsigned short* dst = (unsigned short*)(isWo ? WOB : xb);
    *(ushort4*)&dst[isWo ? j : j - 1048576u] = o;
    return;
  }
  const float* src; short* O; int r0, d0, c0, ldS;
  if (bid < 384) {
    const int z = bid >> 7, t = bid & 127;
    r0 = (t >> 4) * 64; d0 = (t & 15) * 64; ldS = 256;
    const float* S0 = z == 0 ? Vb : z == 1 ? Wb : Ub;
    const float* S1 = z == 0 ? Vt : z == 1 ? Wt : Ut;
    O = z == 0 ? VCT : z == 1 ? WCT : UCT;
    src = (r0 < 256) ? S0 : S1; c0 = r0 & 255;
  } else if (bid < 448) {
    const int t = bid - 384;
    r0 = (t >> 4) * 64; d0 = (t & 15) * 64; ldS = 256;
    src = Xt; c0 = r0; O = PbXt;
  } else {
    const int t = bid - 448;
    const int w = t >> 8, tt = t & 255;
    r0 = (tt >> 4) * 64; d0 = (tt & 15) * 64; ldS = 1024;
    src = w ? Wk : Wq; O = w ? WKT : WQT; c0 = r0;
  }
  __shared__ float Ts[64][65];
  const int lr = tid >> 4;
  const int lc = (tid & 15) * 4;
#pragma unroll
  for (int p = 0; p < 4; ++p) {
    const int row = lr + p * 16;
    const float4 v = *(const float4*)&src[(size_t)(d0 + row) * ldS + c0 + lc];
    Ts[row][lc + 0] = v.x; Ts[row][lc + 1] = v.y;
    Ts[row][lc + 2] = v.z; Ts[row][lc + 3] = v.w;
  }
  __syncthreads();
#pragma unroll
  for (int p = 0; p < 4; ++p) {
    const int ri = lr + p * 16;
    ushort4 o;
    o.x = f2bf(Ts[lc + 0][ri]); o.y = f2bf(Ts[lc + 1][ri]);
    o.z = f2bf(Ts[lc + 2][ri]); o.w = f2bf(Ts[lc + 3][ri]);
    *(ushort4*)&((unsigned short*)O)[(size_t)(r0 + ri) * 1024 + d0 + lc] = o;
  }
}

// scr[b][seg][c] -> exclusive prefix over segs (per batch, per col)
__global__ void cumsum_s2(float* __restrict__ scr) {
  const int lane = threadIdx.x;
  const int cg = blockIdx.x, b = blockIdx.z;
  const int c = cg * 64 + lane;
  float run = 0.f;
  for (int seg = 0; seg < 32; ++seg) {
    const size_t idx = (size_t)(b * 32 + seg) * 768 + c;
    const float v = scr[idx];
    scr[idx] = run;
    run += v;
  }
}

// ===== fused scan stage-3 + combine -> Eb, bf16 Y in, depth-8 row prefetch ====
// block (seg, b), 256 thr: thread = c2 in [0,256). Named prefetch slots only
// (rule #20: no runtime-indexed register arrays).
#define LOADR(s, t) {                                                   \
    const unsigned short* p_ = yb + (size_t)(t) * NCAT;                 \
    ab##s = bf2f(p_[c2]);        at##s = bf2f(p_[256 + c2]);            \
    cb##s = bf2f(p_[512 + c2]);  ct##s = bf2f(p_[768 + c2]);            \
    zt##s = bf2f(p_[1024 + c2]); }
#define STEPR(s, t) {                                                   \
    run_cb += cb##s; run_ct += ct##s; run_zt += zt##s;                  \
    const float inv_ = 1.0f / (float)(segbase + (t) + 1);               \
    unsigned short* er_ = Eb + (row0 + (t)) * 512;                      \
    er_[c2]       = f2bf(ab##s * run_cb);                               \
    er_[256 + c2] = f2bf(al * at##s * (run_zt * inv_) * run_ct); }
__global__ __launch_bounds__(256) void scan_combine(
    const unsigned short* __restrict__ Y, const float* __restrict__ scr,
    unsigned short* __restrict__ Eb, const float* __restrict__ alpha_p) {
  const float al = *alpha_p;
  const int c2 = threadIdx.x;
  const int seg = blockIdx.x, b = blockIdx.y;
  const int segbase = seg * 64;
  const float* sc = scr + (size_t)(b * 32 + seg) * 768;
  float run_cb = sc[c2];
  float run_ct = sc[256 + c2];
  float run_zt = sc[512 + c2];
  const size_t row0 = (size_t)(b * TSEQ + segbase);
  const unsigned short* yb = Y + row0 * NCAT;
  float ab0, at0, cb0, ct0, zt0, ab1, at1, cb1, ct1, zt1;
  float ab2, at2, cb2, ct2, zt2, ab3, at3, cb3, ct3, zt3;
  float ab4, at4, cb4, ct4, zt4, ab5, at5, cb5, ct5, zt5;
  float ab6, at6, cb6, ct6, zt6, ab7, at7, cb7, ct7, zt7;
  LOADR(0, 0) LOADR(1, 1) LOADR(2, 2) LOADR(3, 3)
  LOADR(4, 4) LOADR(5, 5) LOADR(6, 6) LOADR(7, 7)
  for (int t = 0; t < 64; t += 8) {
    STEPR(0, t + 0) if (t + 8 < 64)  LOADR(0, t + 8)
    STEPR(1, t + 1) if (t + 9 < 64)  LOADR(1, t + 9)
    STEPR(2, t + 2) if (t + 10 < 64) LOADR(2, t + 10)
    STEPR(3, t + 3) if (t + 11 < 64) LOADR(3, t + 11)
    STEPR(4, t + 4) if (t + 12 < 64) LOADR(4, t + 12)
    STEPR(5, t + 5) if (t + 13 < 64) LOADR(5, t + 13)
    STEPR(6, t + 6) if (t + 14 < 64) LOADR(6, t + 14)
    STEPR(7, t + 7) if (t + 15 < 64) LOADR(7, t + 15)
  }
}
#undef LOADR
#undef STEPR

// ================= launch =================
extern "C" void kernel_launch(void* const* d_in, const int* in_sizes, int n_in,
                              void* d_out, int out_size, void* d_ws, size_t ws_size,
                              hipStream_t stream) {
  const float* x      = (const float*)d_in[0];
  const float* Wq     = (const float*)d_in[1];
  const float* Wk     = (const float*)d_in[2];
  const float* Wo     = (const float*)d_in[3];
  const float* Ub     = (const float*)d_in[4];
  const float* Vb     = (const float*)d_in[5];
  const float* Wb     = (const float*)d_in[6];
  const float* bias_b = (const float*)d_in[7];
  const float* Ut     = (const float*)d_in[8];
  const float* Vt     = (const float*)d_in[9];
  const float* Wt     = (const float*)d_in[10];
  const float* Xt     = (const float*)d_in[11];
  const float* bias_t = (const float*)d_in[12];
  const float* alpha  = (const float*)d_in[13];
  float* out = (float*)d_out;
  float* ws  = (float*)d_ws;

  short* WQT = (short*)(ws + OFF_WQT);
  short* WKT = (short*)(ws + OFF_WKT);
  short* WOB = (short*)(ws + OFF_WOB);
  short* VCT = (short*)(ws + OFF_VCT);
  short* WCT = (short*)(ws + OFF_WCT);
  short* UCT = (short*)(ws + OFF_UCT);
  float* b2  = ws + OFF_B2;
  short* Pb  = (short*)(ws + OFF_PB);
  short* Gb  = (short*)(ws + OFF_GB);
  unsigned short* Yb = (unsigned short*)(ws + OFF_Y);
  float* scr = ws + OFF_SCR;
  short* xb  = (short*)(ws + OFF_XB);
  short* Eb  = (short*)(ws + OFF_EB);

  // 1. transposes + f2b(Wo) + f2b(x) + bias projection
  prep_all<<<11200, 256, 0, stream>>>(Vb, Vt, Wb, Wt, Ub, Ut, Xt, Wq, Wk, Wo, x,
                                      bias_b, bias_t, alpha,
                                      VCT, WCT, UCT, Pb + (size_t)1024 * 1024,
                                      WQT, WKT, WOB, xb, b2);
  // 2. batched prep GEMMs (Pb rows 0..1023, Gb)
  prep_mfma<<<96, 256, 0, stream>>>(VCT, WQT, WCT, WKT, WOB, UCT, Pb, Gb);
  // 3. Y(bf16) = xb @ Pb^T (M=8192,N=1280,K=1024) + fused per-seg col sums
  mfma_nt<0, 1, 1><<<dim3(NCAT / 128, MROWS / 128), 256, 0, stream>>>(
      xb, Pb, Yb, 1024, 1024, 1024, NCAT, nullptr, scr);
  // 4. exclusive prefix over segments
  cumsum_s2<<<dim3(12, 1, NBATCH), 64, 0, stream>>>(scr);
  // 5. fused scan+combine -> Eb
  scan_combine<<<dim3(32, NBATCH), 256, 0, stream>>>(Yb, scr, (unsigned short*)Eb, alpha);
  // 6. out = diag(1/counts) * (Eb @ Gb^T) + b2  (M=8192,N=1024,K=512)
  mfma_nt<1, 0, 0><<<dim3(1024 / 128, MROWS / 128), 256, 0, stream>>>(
      Eb, Gb, out, 512, 512, 512, 1024, b2, nullptr);
}

// Round 10
// 196.710 us; speedup vs baseline: 1.0376x; 1.0376x over previous
//
#include <hip/hip_runtime.h>

// Problem constants
#define NBATCH  4
#define TSEQ    2048
#define MROWS   8192
#define NCAT    1280              // 512 (a_b|a_t) + 512 (c_b|c_t) + 256 (z_t)
#define NE      512

// ---- workspace layout (float offsets) ----
#define OFF_WQT   0u                          // Wq^T bf16 [1024][1024]
#define OFF_WKT   524288u                     // Wk^T bf16 [1024][1024]
#define OFF_WOB   1048576u                    // Wo   bf16 [1024][1024]
#define OFF_VCT   1572864u                    // Vc^T bf16 [512][1024]
#define OFF_WCT   1835008u                    // Wc^T bf16 [512][1024]
#define OFF_UCT   2097152u                    // Uc^T bf16 [512][1024]
#define OFF_B2    2359296u                    // [1024] f32
#define OFF_PB    2360320u                    // PcatT bf16 [1280][1024]
#define OFF_GB    3015680u                    // G bf16 [1024][512]
#define OFF_Y     3277824u                    // Y bf16 [8192][1280]
#define OFF_SCR   13763584u                   // f32 [4][32][768] raw seg sums
#define OFF_XB    13861888u                   // x bf16 [8192][1024]
#define OFF_EB    OFF_XB                      // E bf16 [8192][512] (aliases xb)

typedef __attribute__((ext_vector_type(8))) short bf16x8;
typedef __attribute__((ext_vector_type(4))) float f32x4;

__device__ __forceinline__ unsigned short f2bf(float f) {
  union { float f; unsigned u; } v; v.f = f;
  return (unsigned short)((v.u + 0x7fff + ((v.u >> 16) & 1)) >> 16);  // RNE
}
__device__ __forceinline__ float bf2f(unsigned short u) {
  union { unsigned u; float f; } v; v.u = ((unsigned)u) << 16;
  return v.f;
}

__device__ __forceinline__ void gload16(const void* g, void* l) {
  __builtin_amdgcn_global_load_lds(
      (const __attribute__((address_space(1))) unsigned*)g,
      (__attribute__((address_space(3))) unsigned*)l, 16, 0, 0);
}

// ===== bf16 MFMA NT tile: BK=64, 8-chunk swizzle (0-conflict), depth-2 =======
// counted-vmcnt pipeline. C[m0:+128][n0:+128] = A[M][K]*B[N][K]^T.
// 4 waves (2x2), wave 64x64. LDS [128][64] shorts/tile (128B rows, 8x16B
// chunks): source chunk pre-swizzled (chunk ^ row&7 -> same row, no extra
// HBM), gload_lds dest linear, ds_read XORs the same involution ->
// conflict-free (measured 0, round 6). Per tile each thread issues 8
// global_load_lds. Steady state: STAGE(t+1) then vmcnt(8) = tile-t's 8
// retired, t+1's 8 IN FLIGHT across the barrier (T4); vmcnt(0) only at tail.
// Raw s_barrier only; ds_read->MFMA waits left to compiler (m97 evidence).
// Buffer hazard (2 bufs): STAGE(t+1) rewrites buf((t+1)&1), last read at
// COMPUTE(t-1), sealed by iter t-1's trailing barrier.  Requires nt >= 1.
// EPI: C = acc / ((m & 2047)+1) + bias[n].  OBF: C is bf16.
// CS: for n0>=512 write 64-row column sums to scr[b][seg][col-512] (raw).
template <int EPI, int OBF, int CS>
__device__ __forceinline__ void mfma_tile(
    const short* __restrict__ A, const short* __restrict__ B, void* __restrict__ Cv,
    int K, int ldA, int ldB, int ldC, int m0, int n0,
    const float* __restrict__ bias, float* __restrict__ scr, short* L) {
  const int tid = threadIdx.x;
  const int l = tid & 63;
  const int wv = tid >> 6;
  const int wm = (wv >> 1) * 64, wn = (wv & 1) * 64;
  const int srow = tid >> 3;            // 0..31 (plus p*32)
  const int schk = tid & 7;             // 16B chunk 0..7 within 128B row
  const int arow = wm + (l & 15), brow = wn + (l & 15);
  const int kq = l >> 4;                // 0..3

  f32x4 acc[4][4] = {};

#define STAGE(k0, buf) do {                                                  \
    short* As_ = L + (buf) * 16384;                                          \
    short* Bs_ = As_ + 8192;                                                 \
    _Pragma("unroll")                                                        \
    for (int p = 0; p < 4; ++p) {                                            \
      const int r = p * 32 + srow;                                           \
      const int sw = (schk ^ (r & 7)) * 8;                                   \
      gload16(A + (size_t)(m0 + r) * ldA + (k0) + sw, As_ + r * 64 + schk * 8); \
      gload16(B + (size_t)(n0 + r) * ldB + (k0) + sw, Bs_ + r * 64 + schk * 8); \
    }                                                                        \
  } while (0)

#define COMPUTE(buf) do {                                                    \
    short* As_ = L + (buf) * 16384;                                          \
    short* Bs_ = As_ + 8192;                                                 \
    _Pragma("unroll")                                                        \
    for (int h = 0; h < 2; ++h) {                                            \
      bf16x8 af[4], bfr[4];                                                  \
      _Pragma("unroll")                                                      \
      for (int m = 0; m < 4; ++m) {                                          \
        const int r = arow + m * 16;                                         \
        af[m] = *(const bf16x8*)&As_[r * 64 + (((h * 4 + kq) ^ (r & 7)) * 8)]; \
      }                                                                      \
      _Pragma("unroll")                                                      \
      for (int n = 0; n < 4; ++n) {                                          \
        const int r = brow + n * 16;                                         \
        bfr[n] = *(const bf16x8*)&Bs_[r * 64 + (((h * 4 + kq) ^ (r & 7)) * 8)]; \
      }                                                                      \
      _Pragma("unroll")                                                      \
      for (int m = 0; m < 4; ++m)                                            \
        _Pragma("unroll")                                                    \
        for (int n = 0; n < 4; ++n)                                          \
          acc[m][n] = __builtin_amdgcn_mfma_f32_16x16x32_bf16(af[m], bfr[n], acc[m][n], 0, 0, 0); \
    }                                                                        \
  } while (0)

  STAGE(0, 0);
  const int nt = K >> 6;
  for (int t = 0; t < nt; ++t) {
    if (t + 1 < nt) {
      STAGE((t + 1) << 6, (t + 1) & 1);
      asm volatile("s_waitcnt vmcnt(8)" ::: "memory");   // tile t ready; 8 in flight
    } else {
      asm volatile("s_waitcnt vmcnt(0)" ::: "memory");   // tail drain
    }
    asm volatile("s_barrier" ::: "memory");
    COMPUTE(t & 1);
    asm volatile("s_barrier" ::: "memory");
  }
#undef STAGE
#undef COMPUTE

  // epilogue. C/D layout: col = l&15, row = (l>>4)*4 + j
  const int cc = wn + (l & 15);
  const int crb = wm + (l >> 4) * 4;
#pragma unroll
  for (int m = 0; m < 4; ++m) {
#pragma unroll
    for (int j = 0; j < 4; ++j) {
      const int gm = m0 + crb + m * 16 + j;
      float inv = 1.0f;
      if (EPI) inv = 1.0f / (float)((gm & (TSEQ - 1)) + 1);
#pragma unroll
      for (int n = 0; n < 4; ++n) {
        const int gn = n0 + cc + n * 16;
        float v = acc[m][n][j];
        if (EPI) v = v * inv + bias[gn];
        if (OBF) ((short*)Cv)[(size_t)gm * ldC + gn] = (short)f2bf(v);
        else     ((float*)Cv)[(size_t)gm * ldC + gn] = v;
      }
    }
  }
  // fused cumsum stage-1: 64-row column sums of this wave's block (f32 acc)
  if (CS && n0 >= 512) {
    const int bb = (m0 + wm) >> 11;
    const int seg = ((m0 + wm) & (TSEQ - 1)) >> 6;
    float* sp = scr + (size_t)(bb * 32 + seg) * 768 + (n0 - 512);
#pragma unroll
    for (int n = 0; n < 4; ++n) {
      float s = 0.f;
#pragma unroll
      for (int m = 0; m < 4; ++m)
#pragma unroll
        for (int j = 0; j < 4; ++j) s += acc[m][n][j];
      s += __shfl_xor(s, 16, 64);
      s += __shfl_xor(s, 32, 64);
      if (l < 16) sp[cc + n * 16] = s;
    }
  }
}

// XCD-aware bijective swizzle of the linearized block id (nwg % 8 == 0).
__device__ __forceinline__ void xcd_swizzle(int& bx, int& by) {
  const int gx = gridDim.x;
  const int nwg = gx * gridDim.y;
  const int n = by * gx + bx;
  const int q = nwg >> 3;
  const int s = (n & 7) * q + (n >> 3);
  bx = s % gx; by = s / gx;
}

template <int EPI, int OBF, int CS>
__global__ __launch_bounds__(256) void mfma_nt(
    const short* __restrict__ A, const short* __restrict__ B,
    void* __restrict__ C, int K, int ldA, int ldB, int ldC,
    const float* __restrict__ bias, float* __restrict__ scr) {
  __shared__ short L[32768];            // 64 KB: 2 bufs x (A+B)
  int bx = blockIdx.x, by = blockIdx.y;
  xcd_swizzle(bx, by);
  mfma_tile<EPI, OBF, CS>(A, B, C, K, ldA, ldB, ldC,
                          by * 128, bx * 128, bias, scr, L);
}

// prep2: blocks 0..95 = 3 prep GEMMs x 32 tiles (K=1024, bf16 out);
// blocks 96..8287 = f2b(x) (fills the CUs left idle by the 96 GEMM blocks).
__global__ __launch_bounds__(256) void prep2(
    const short* __restrict__ VCT, const short* __restrict__ WQT,
    const short* __restrict__ WCT, const short* __restrict__ WKT,
    const short* __restrict__ WOB, const short* __restrict__ UCT,
    short* __restrict__ Pb, short* __restrict__ Gb,
    const float* __restrict__ x, short* __restrict__ xb) {
  __shared__ short L[32768];
  const int bid = blockIdx.x;
  if (bid >= 96) {
    const size_t j = ((size_t)(bid - 96) * 256 + threadIdx.x) * 4;
    const float4 v = *(const float4*)&x[j];
    ushort4 o;
    o.x = f2bf(v.x); o.y = f2bf(v.y); o.z = f2bf(v.z); o.w = f2bf(v.w);
    *(ushort4*)&((unsigned short*)xb)[j] = o;
    return;
  }
  const int g = bid >> 5, t = bid & 31;
  if (g == 0)
    mfma_tile<0, 1, 0>(VCT, WQT, Pb, 1024, 1024, 1024, 1024,
                       (t >> 3) * 128, (t & 7) * 128, nullptr, nullptr, L);
  else if (g == 1)
    mfma_tile<0, 1, 0>(WCT, WKT, Pb + (size_t)512 * 1024, 1024, 1024, 1024, 1024,
                       (t >> 3) * 128, (t & 7) * 128, nullptr, nullptr, L);
  else
    mfma_tile<0, 1, 0>(WOB, UCT, Gb, 1024, 1024, 1024, 512,
                       (t >> 2) * 128, (t & 3) * 128, nullptr, nullptr, L);
}

// ===== prep_all: transposes + f2b(Wo) + bias_proj, one launch ================
// bid<960: transpose panels; [960,1984): f2b Wo; [1984,3008): bias_proj.
__global__ __launch_bounds__(256) void prep_all(
    const float* __restrict__ Vb, const float* __restrict__ Vt,
    const float* __restrict__ Wb, const float* __restrict__ Wt,
    const float* __restrict__ Ub, const float* __restrict__ Ut,
    const float* __restrict__ Xt, const float* __restrict__ Wq,
    const float* __restrict__ Wk, const float* __restrict__ Wo,
    const float* __restrict__ bias_b, const float* __restrict__ bias_t,
    const float* __restrict__ alpha_p,
    short* __restrict__ VCT, short* __restrict__ WCT, short* __restrict__ UCT,
    short* __restrict__ PbXt, short* __restrict__ WQT, short* __restrict__ WKT,
    short* __restrict__ WOB, float* __restrict__ b2) {
  const int bid = blockIdx.x;
  const int tid = threadIdx.x;
  if (bid >= 1984) {                        // bias_proj: d = bid - 1984
    const float al = *alpha_p;
    const int d = bid - 1984;
    float s = 0.f;
    for (int e = tid; e < 1024; e += 256)
      s += Wo[(size_t)d * 1024 + e] * (bias_b[e] + al * bias_t[e]);
    __shared__ float red[256];
    red[tid] = s; __syncthreads();
    for (int off = 128; off > 0; off >>= 1) {
      if (tid < off) red[tid] += red[tid + off];
      __syncthreads();
    }
    if (tid == 0) b2[d] = red[0];
    return;
  }
  if (bid >= 960) {                         // f2b: Wo (1M floats)
    const size_t j = ((size_t)(bid - 960) * 256 + tid) * 4;
    const float4 v = *(const float4*)&Wo[j];
    ushort4 o;
    o.x = f2bf(v.x); o.y = f2bf(v.y); o.z = f2bf(v.z); o.w = f2bf(v.w);
    *(ushort4*)&((unsigned short*)WOB)[j] = o;
    return;
  }
  const float* src; short* O; int r0, d0, c0, ldS;
  if (bid < 384) {
    const int z = bid >> 7, t = bid & 127;
    r0 = (t >> 4) * 64; d0 = (t & 15) * 64; ldS = 256;
    const float* S0 = z == 0 ? Vb : z == 1 ? Wb : Ub;
    const float* S1 = z == 0 ? Vt : z == 1 ? Wt : Ut;
    O = z == 0 ? VCT : z == 1 ? WCT : UCT;
    src = (r0 < 256) ? S0 : S1; c0 = r0 & 255;
  } else if (bid < 448) {
    const int t = bid - 384;
    r0 = (t >> 4) * 64; d0 = (t & 15) * 64; ldS = 256;
    src = Xt; c0 = r0; O = PbXt;
  } else {
    const int t = bid - 448;
    const int w = t >> 8, tt = t & 255;
    r0 = (tt >> 4) * 64; d0 = (tt & 15) * 64; ldS = 1024;
    src = w ? Wk : Wq; O = w ? WKT : WQT; c0 = r0;
  }
  __shared__ float Ts[64][65];
  const int lr = tid >> 4;
  const int lc = (tid & 15) * 4;
#pragma unroll
  for (int p = 0; p < 4; ++p) {
    const int row = lr + p * 16;
    const float4 v = *(const float4*)&src[(size_t)(d0 + row) * ldS + c0 + lc];
    Ts[row][lc + 0] = v.x; Ts[row][lc + 1] = v.y;
    Ts[row][lc + 2] = v.z; Ts[row][lc + 3] = v.w;
  }
  __syncthreads();
#pragma unroll
  for (int p = 0; p < 4; ++p) {
    const int ri = lr + p * 16;
    ushort4 o;
    o.x = f2bf(Ts[lc + 0][ri]); o.y = f2bf(Ts[lc + 1][ri]);
    o.z = f2bf(Ts[lc + 2][ri]); o.w = f2bf(Ts[lc + 3][ri]);
    *(ushort4*)&((unsigned short*)O)[(size_t)(r0 + ri) * 1024 + d0 + lc] = o;
  }
}

// ===== fused scan: self-prefix + stage-3 + combine -> Eb, depth-8 prefetch ====
// block (seg, b), 256 thr. scr holds RAW per-seg column sums; each block sums
// rows [0, seg) itself (same addition order as the old s2 kernel).
#define LOADR(s, t) {                                                   \
    const unsigned short* p_ = yb + (size_t)(t) * NCAT;                 \
    ab##s = bf2f(p_[c2]);        at##s = bf2f(p_[256 + c2]);            \
    cb##s = bf2f(p_[512 + c2]);  ct##s = bf2f(p_[768 + c2]);            \
    zt##s = bf2f(p_[1024 + c2]); }
#define STEPR(s, t) {                                                   \
    run_cb += cb##s; run_ct += ct##s; run_zt += zt##s;                  \
    const float inv_ = 1.0f / (float)(segbase + (t) + 1);               \
    unsigned short* er_ = Eb + (row0 + (t)) * 512;                      \
    er_[c2]       = f2bf(ab##s * run_cb);                               \
    er_[256 + c2] = f2bf(al * at##s * (run_zt * inv_) * run_ct); }
__global__ __launch_bounds__(256) void scan_combine(
    const unsigned short* __restrict__ Y, const float* __restrict__ scr,
    unsigned short* __restrict__ Eb, const float* __restrict__ alpha_p) {
  const float al = *alpha_p;
  const int c2 = threadIdx.x;
  const int seg = blockIdx.x, b = blockIdx.y;
  const int segbase = seg * 64;
  float run_cb = 0.f, run_ct = 0.f, run_zt = 0.f;
  for (int s = 0; s < seg; ++s) {
    const float* sr = scr + (size_t)(b * 32 + s) * 768;
    run_cb += sr[c2]; run_ct += sr[256 + c2]; run_zt += sr[512 + c2];
  }
  const size_t row0 = (size_t)(b * TSEQ + segbase);
  const unsigned short* yb = Y + row0 * NCAT;
  float ab0, at0, cb0, ct0, zt0, ab1, at1, cb1, ct1, zt1;
  float ab2, at2, cb2, ct2, zt2, ab3, at3, cb3, ct3, zt3;
  float ab4, at4, cb4, ct4, zt4, ab5, at5, cb5, ct5, zt5;
  float ab6, at6, cb6, ct6, zt6, ab7, at7, cb7, ct7, zt7;
  LOADR(0, 0) LOADR(1, 1) LOADR(2, 2) LOADR(3, 3)
  LOADR(4, 4) LOADR(5, 5) LOADR(6, 6) LOADR(7, 7)
  for (int t = 0; t < 64; t += 8) {
    STEPR(0, t + 0) if (t + 8 < 64)  LOADR(0, t + 8)
    STEPR(1, t + 1) if (t + 9 < 64)  LOADR(1, t + 9)
    STEPR(2, t + 2) if (t + 10 < 64) LOADR(2, t + 10)
    STEPR(3, t + 3) if (t + 11 < 64) LOADR(3, t + 11)
    STEPR(4, t + 4) if (t + 12 < 64) LOADR(4, t + 12)
    STEPR(5, t + 5) if (t + 13 < 64) LOADR(5, t + 13)
    STEPR(6, t + 6) if (t + 14 < 64) LOADR(6, t + 14)
    STEPR(7, t + 7) if (t + 15 < 64) LOADR(7, t + 15)
  }
}
#undef LOADR
#undef STEPR

// ================= launch =================
extern "C" void kernel_launch(void* const* d_in, const int* in_sizes, int n_in,
                              void* d_out, int out_size, void* d_ws, size_t ws_size,
                              hipStream_t stream) {
  const float* x      = (const float*)d_in[0];
  const float* Wq     = (const float*)d_in[1];
  const float* Wk     = (const float*)d_in[2];
  const float* Wo     = (const float*)d_in[3];
  const float* Ub     = (const float*)d_in[4];
  const float* Vb     = (const float*)d_in[5];
  const float* Wb     = (const float*)d_in[6];
  const float* bias_b = (const float*)d_in[7];
  const float* Ut     = (const float*)d_in[8];
  const float* Vt     = (const float*)d_in[9];
  const float* Wt     = (const float*)d_in[10];
  const float* Xt     = (const float*)d_in[11];
  const float* bias_t = (const float*)d_in[12];
  const float* alpha  = (const float*)d_in[13];
  float* out = (float*)d_out;
  float* ws  = (float*)d_ws;

  short* WQT = (short*)(ws + OFF_WQT);
  short* WKT = (short*)(ws + OFF_WKT);
  short* WOB = (short*)(ws + OFF_WOB);
  short* VCT = (short*)(ws + OFF_VCT);
  short* WCT = (short*)(ws + OFF_WCT);
  short* UCT = (short*)(ws + OFF_UCT);
  float* b2  = ws + OFF_B2;
  short* Pb  = (short*)(ws + OFF_PB);
  short* Gb  = (short*)(ws + OFF_GB);
  unsigned short* Yb = (unsigned short*)(ws + OFF_Y);
  float* scr = ws + OFF_SCR;
  short* xb  = (short*)(ws + OFF_XB);
  short* Eb  = (short*)(ws + OFF_EB);

  // 1. transposes + f2b(Wo) + bias projection
  prep_all<<<3008, 256, 0, stream>>>(Vb, Vt, Wb, Wt, Ub, Ut, Xt, Wq, Wk, Wo,
                                     bias_b, bias_t, alpha,
                                     VCT, WCT, UCT, Pb + (size_t)1024 * 1024,
                                     WQT, WKT, WOB, b2);
  // 2. prep GEMMs (96 blocks) + f2b(x) (8192 blocks) in one launch
  prep2<<<8288, 256, 0, stream>>>(VCT, WQT, WCT, WKT, WOB, UCT, Pb, Gb, x, xb);
  // 3. Y(bf16) = xb @ Pb^T (M=8192,N=1280,K=1024) + fused per-seg col sums
  mfma_nt<0, 1, 1><<<dim3(NCAT / 128, MROWS / 128), 256, 0, stream>>>(
      xb, Pb, Yb, 1024, 1024, 1024, NCAT, nullptr, scr);
  // 4. fused prefix + scan + combine -> Eb
  scan_combine<<<dim3(32, NBATCH), 256, 0, stream>>>(Yb, scr, (unsigned short*)Eb, alpha);
  // 5. out = diag(1/counts) * (Eb @ Gb^T) + b2  (M=8192,N=1024,K=512)
  mfma_nt<1, 0, 0><<<dim3(1024 / 128, MROWS / 128), 256, 0, stream>>>(
      Eb, Gb, out, 512, 512, 512, 1024, b2, nullptr);
}